// Round 1
// baseline (228.825 us; speedup 1.0000x reference)
//
#include <hip/hip_runtime.h>
#include <cstdint>
#include <climits>

// LeakyTopKActivation: out = x * mask * GAIN, mask = 1.0 on per-row top-k
// (k = 614 of 4096, stable ties by lowest index), LEAK=0.1 elsewhere.
// One 256-thread block per row; row lives in registers (16 floats/thread).
// Exact selection via bracketed histogram [0.7,1.4] (threshold ~= 1.036 for
// N(0,1) rows) + tiny LDS gather/sort; exact bit-level binary-search fallback
// if the bracket ever misses (correctness never depends on the distribution).

namespace {
constexpr int   N_FEAT  = 4096;
constexpr int   KSEL    = 614;      // max(int(4096*0.15),1)
constexpr int   NB      = 256;      // histogram bins in bracket
constexpr int   THREADS = 256;
constexpr int   NCHUNK  = 4;        // float4 per thread
constexpr int   EPT     = 16;       // elements per thread
constexpr float LO_BR   = 0.70f;
constexpr float HI_BR   = 1.40f;
constexpr float GAINF   = 3.0f;
constexpr float LEAKG   = 0.3f;     // LEAK * GAIN
constexpr int   M_LIST  = 256;      // max gathered candidates in selected bin
}

__device__ __forceinline__ uint32_t f2key(float f) {
    uint32_t u = __float_as_uint(f);
    return u ^ ((uint32_t)(((int32_t)u) >> 31) | 0x80000000u);
}

__global__ __launch_bounds__(THREADS)
void leaky_topk_kernel(const float* __restrict__ x, float* __restrict__ out) {
    const int row  = blockIdx.x;
    const int tid  = threadIdx.x;
    const int lane = tid & 63;
    const int wv   = tid >> 6;

    const float4* __restrict__ xv = (const float4*)(x + (size_t)row * N_FEAT);
    float4* __restrict__ ov       = (float4*)(out + (size_t)row * N_FEAT);

    __shared__ unsigned int hist[NB];
    __shared__ float        lvals[M_LIST];
    __shared__ int          lidx[M_LIST];
    __shared__ unsigned int wtot[4];
    __shared__ unsigned int sh_above;
    __shared__ unsigned int sh_listcnt;
    __shared__ int          sh_bin;
    __shared__ int          sh_S1;
    __shared__ int          sh_flag;
    __shared__ float        sh_T;
    __shared__ int          sh_cut;
    __shared__ unsigned int sh_red;

    // Coalesced load: wave's 64 lanes read 64 consecutive float4s.
    float4 v[NCHUNK];
    #pragma unroll
    for (int j = 0; j < NCHUNK; ++j) v[j] = xv[j * THREADS + tid];

    hist[tid] = 0u;
    if (tid == 0) { sh_above = 0u; sh_listcnt = 0u; sh_flag = 0; }
    __syncthreads();

    // Bracketed histogram; >=HI counted without atomics.
    const float invw = (float)NB / (HI_BR - LO_BR);
    unsigned int ca = 0;
    #pragma unroll
    for (int j = 0; j < NCHUNK; ++j) {
        const float* e = (const float*)&v[j];
        #pragma unroll
        for (int q = 0; q < 4; ++q) {
            float f = e[q];
            if (f >= HI_BR) {
                ++ca;
            } else if (f >= LO_BR) {
                int b = (int)((f - LO_BR) * invw);
                if (b > NB - 1) b = NB - 1;       // fp-rounding safety
                atomicAdd(&hist[b], 1u);
            }
        }
    }
    #pragma unroll
    for (int d = 32; d > 0; d >>= 1) ca += __shfl_down(ca, d, 64);
    if (lane == 0) atomicAdd(&sh_above, ca);
    __syncthreads();

    const int K2 = KSEL - (int)sh_above;   // still needed within/below bracket

    // Suffix sums S[t] = sum hist[t..255] via per-wave shfl + wave totals.
    const int h = (int)hist[tid];
    int s = h;
    #pragma unroll
    for (int d = 1; d < 64; d <<= 1) {
        int o = __shfl_down(s, d, 64);
        if (lane + d < 64) s += o;
    }
    if (lane == 0) wtot[wv] = (unsigned int)s;
    __syncthreads();
    int off = 0;
    #pragma unroll
    for (int w = 0; w < 4; ++w) if (w > wv) off += (int)wtot[w];
    const int Stot = (int)(wtot[0] + wtot[1] + wtot[2] + wtot[3]);
    const int S  = s + off;    // >= count in bins [tid..255]
    const int S1 = S - h;      // count in bins (tid..255]

    if (tid == 0 && (K2 <= 0 || Stot < K2)) sh_flag = 1;  // k-th outside bracket
    if (K2 > 0 && S >= K2 && S1 < K2) { sh_bin = tid; sh_S1 = S1; }  // unique
    __syncthreads();

    bool fallback = (sh_flag != 0);
    int bsel = 0, cin = 0, rr = 0;
    if (!fallback) {
        bsel = sh_bin;
        cin  = (int)hist[bsel];
        rr   = K2 - sh_S1;                  // rr-th largest inside bin, 1..cin
        if (cin > M_LIST) fallback = true;  // uniform decision
    }

    if (!fallback) {
        // Gather the selected bin's (value, index) pairs (expected ~3).
        #pragma unroll
        for (int j = 0; j < NCHUNK; ++j) {
            const float* e = (const float*)&v[j];
            #pragma unroll
            for (int q = 0; q < 4; ++q) {
                float f = e[q];
                if (f >= LO_BR && f < HI_BR) {
                    int b = (int)((f - LO_BR) * invw);
                    if (b > NB - 1) b = NB - 1;
                    if (b == bsel) {
                        unsigned int p = atomicAdd(&sh_listcnt, 1u);
                        lvals[p] = f;
                        lidx[p]  = (j * THREADS + tid) * 4 + q;
                    }
                }
            }
        }
        __syncthreads();
        if (tid == 0) {
            int n = (int)sh_listcnt;   // == cin <= M_LIST
            // insertion sort: value desc, index asc (top_k stable order)
            for (int i = 1; i < n; ++i) {
                float fv = lvals[i]; int fi = lidx[i];
                int j2 = i - 1;
                while (j2 >= 0 && (lvals[j2] < fv ||
                       (lvals[j2] == fv && lidx[j2] > fi))) {
                    lvals[j2 + 1] = lvals[j2]; lidx[j2 + 1] = lidx[j2]; --j2;
                }
                lvals[j2 + 1] = fv; lidx[j2 + 1] = fi;
            }
            float T = lvals[rr - 1];
            int cut = INT_MAX;  // accept all equals unless a tied one is excluded
            if (rr < n && lvals[rr] == T) cut = lidx[rr - 1] + 1;
            sh_T = T; sh_cut = cut;
        }
        __syncthreads();
        const float T  = sh_T;
        const int  cut = sh_cut;
        #pragma unroll
        for (int j = 0; j < NCHUNK; ++j) {
            const float* e = (const float*)&v[j];
            float4 o;
            float* oe = (float*)&o;
            #pragma unroll
            for (int q = 0; q < 4; ++q) {
                float f = e[q];
                int g = (j * THREADS + tid) * 4 + q;
                bool acc = (f > T) || (f == T && g < cut);
                oe[q] = f * (acc ? GAINF : LEAKG);
            }
            ov[j * THREADS + tid] = o;
        }
        return;
    }

    // ---- exact fallback: bit binary search on order-preserving keys --------
    uint32_t keys[EPT];
    #pragma unroll
    for (int j = 0; j < NCHUNK; ++j) {
        const float* e = (const float*)&v[j];
        #pragma unroll
        for (int q = 0; q < 4; ++q) keys[j * 4 + q] = f2key(e[q]);
    }

    auto blockReduce = [&](unsigned int c) -> int {
        #pragma unroll
        for (int d = 32; d > 0; d >>= 1) c += __shfl_down(c, d, 64);
        if (tid == 0) sh_red = 0u;
        __syncthreads();
        if (lane == 0) atomicAdd(&sh_red, c);
        __syncthreads();
        unsigned int r2 = sh_red;
        __syncthreads();
        return (int)r2;
    };

    auto cntGe = [&](uint32_t thr) -> int {
        unsigned int c = 0;
        #pragma unroll
        for (int i = 0; i < EPT; ++i) c += (keys[i] >= thr) ? 1u : 0u;
        return blockReduce(c);
    };

    uint32_t lo = 0u, hi = 0xFFFFFFFFu;
    while (lo < hi) {                       // find max key with cntGe >= KSEL
        uint32_t d   = hi - lo;
        uint32_t mid = lo + (d >> 1) + (d & 1u);   // upper mid, no overflow
        if (cntGe(mid) >= KSEL) lo = mid; else hi = mid - 1u;
    }
    const uint32_t Tkey = lo;
    const int c_ge = cntGe(Tkey);
    const int c_gt = (Tkey == 0xFFFFFFFFu) ? 0 : cntGe(Tkey + 1u);
    const int need_eq = KSEL - c_gt;
    const int cnt_eq  = c_ge - c_gt;

    int cut = INT_MAX;
    if (need_eq < cnt_eq) {
        // smallest m with count(key==Tkey && g<m) >= need_eq
        int l2 = 0, h2 = N_FEAT;
        while (l2 < h2) {
            int mid = (l2 + h2) >> 1;
            unsigned int c = 0;
            #pragma unroll
            for (int i = 0; i < EPT; ++i) {
                int g = ((i >> 2) * THREADS + tid) * 4 + (i & 3);
                c += (keys[i] == Tkey && g < mid) ? 1u : 0u;
            }
            if (blockReduce(c) >= need_eq) h2 = mid; else l2 = mid + 1;
        }
        cut = l2;
    }

    #pragma unroll
    for (int j = 0; j < NCHUNK; ++j) {
        const float* e = (const float*)&v[j];
        float4 o;
        float* oe = (float*)&o;
        #pragma unroll
        for (int q = 0; q < 4; ++q) {
            float f = e[q];
            uint32_t kk = keys[j * 4 + q];
            int g = (j * THREADS + tid) * 4 + q;
            bool acc = (kk > Tkey) || (kk == Tkey && g < cut);
            oe[q] = f * (acc ? GAINF : LEAKG);
        }
        ov[j * THREADS + tid] = o;
    }
}

extern "C" void kernel_launch(void* const* d_in, const int* in_sizes, int n_in,
                              void* d_out, int out_size, void* d_ws, size_t ws_size,
                              hipStream_t stream) {
    const float* x = (const float*)d_in[0];
    float* out = (float*)d_out;
    const int nrows = in_sizes[0] / N_FEAT;
    leaky_topk_kernel<<<nrows, THREADS, 0, stream>>>(x, out);
}